// Round 1
// baseline (897.450 us; speedup 1.0000x reference)
//
#include <hip/hip_runtime.h>
#include <math.h>

#define D 64

// ---------------------------------------------------------------------------
// Stage 2: scatter-mean numerator — one WAVE per edge, lane = feature.
// Coalesced 64-float gather of X[row], coalesced 64 atomicAdds into agg[col].
// ---------------------------------------------------------------------------
__global__ __launch_bounds__(256) void scatter_agg(
    const float* __restrict__ X, const int* __restrict__ ei,
    float* __restrict__ agg, float* __restrict__ cnt, int n_edges)
{
    int wave = (blockIdx.x * blockDim.x + threadIdx.x) >> 6;
    int lane = threadIdx.x & 63;
    if (wave >= n_edges) return;
    int r = ei[wave];             // source
    int c = ei[n_edges + wave];   // target
    float v = X[(long long)r * D + lane];
    atomicAdd(&agg[(long long)c * D + lane], v);
    if (lane == 0) atomicAdd(&cnt[c], 1.0f);
}

// ---------------------------------------------------------------------------
// Stage 3: h = relu(agg/cnt @ W_l + b + X @ W_r). One wave per node.
// W_l, W_r staged in LDS (32 KiB). a_k/x_k broadcast via __shfl (width 64).
// LDS read sW[k][lane]: stride-1 across 64 lanes = 2-way bank alias = free.
// ---------------------------------------------------------------------------
__global__ __launch_bounds__(256) void linear_relu(
    const float* __restrict__ X, const float* __restrict__ agg,
    const float* __restrict__ cnt, const float* __restrict__ Wl,
    const float* __restrict__ Wr, const float* __restrict__ b,
    float* __restrict__ h, int n)
{
    __shared__ float sWl[D][D];
    __shared__ float sWr[D][D];
    for (int i = threadIdx.x; i < D * D; i += blockDim.x) {
        sWl[i / D][i % D] = Wl[i];
        sWr[i / D][i % D] = Wr[i];
    }
    __syncthreads();

    int lane = threadIdx.x & 63;
    int waveInBlock = threadIdx.x >> 6;
    int wavesPerBlock = blockDim.x >> 6;
    float bj = b[lane];

    for (int node = blockIdx.x * wavesPerBlock + waveInBlock; node < n;
         node += gridDim.x * wavesPerBlock) {
        float inv = 1.0f / fmaxf(cnt[node], 1.0f);
        float a = agg[(long long)node * D + lane] * inv;
        float x = X[(long long)node * D + lane];
        float acc = bj;
        #pragma unroll
        for (int k = 0; k < D; ++k) {
            float ak = __shfl(a, k);
            float xk = __shfl(x, k);
            acc += ak * sWl[k][lane] + xk * sWr[k][lane];
        }
        h[(long long)node * D + lane] = fmaxf(acc, 0.0f);
    }
}

// ---------------------------------------------------------------------------
// Stage 4: edge-wise (h[row]-h[col])^2 scattered (mean numerator) by row.
// ---------------------------------------------------------------------------
__global__ __launch_bounds__(256) void scatter_gate(
    const float* __restrict__ h, const int* __restrict__ ei,
    float* __restrict__ dsum, float* __restrict__ cnt, int n_edges)
{
    int wave = (blockIdx.x * blockDim.x + threadIdx.x) >> 6;
    int lane = threadIdx.x & 63;
    if (wave >= n_edges) return;
    int r = ei[wave];
    int c = ei[n_edges + wave];
    float d = h[(long long)r * D + lane] - h[(long long)c * D + lane];
    atomicAdd(&dsum[(long long)r * D + lane], d * d);   // P = 2: |d|^2 == d*d
    if (lane == 0) atomicAdd(&cnt[r], 1.0f);
}

// ---------------------------------------------------------------------------
// Stage 5: gg = tanh(diff_sum / max(cnt,1))
// ---------------------------------------------------------------------------
__global__ __launch_bounds__(256) void finalize_gate(
    const float* __restrict__ dsum, const float* __restrict__ cnt,
    float* __restrict__ out, int n)
{
    int i = blockIdx.x * blockDim.x + threadIdx.x;
    if (i >= n * D) return;
    int node = i >> 6;
    out[i] = tanhf(dsum[i] / fmaxf(cnt[node], 1.0f));
}

extern "C" void kernel_launch(void* const* d_in, const int* in_sizes, int n_in,
                              void* d_out, int out_size, void* d_ws, size_t ws_size,
                              hipStream_t stream) {
    const float* X  = (const float*)d_in[0];
    const int*   ei = (const int*)d_in[1];
    const float* Wl = (const float*)d_in[2];
    const float* Wr = (const float*)d_in[3];
    const float* b  = (const float*)d_in[4];
    float* out = (float*)d_out;

    int n = in_sizes[0] / D;
    int n_edges = in_sizes[1] / 2;

    // workspace layout (floats):
    // [agg_sum: n*D][cnt_col: n][diff_sum: n*D][cnt_row: n][h: n*D]
    float* ws = (float*)d_ws;
    float* agg     = ws;
    float* cnt_col = agg + (size_t)n * D;
    float* dsum    = cnt_col + n;
    float* cnt_row = dsum + (size_t)n * D;
    float* h       = cnt_row + n;

    size_t zero_bytes = ((size_t)2 * n * D + 2 * (size_t)n) * sizeof(float);
    hipMemsetAsync(d_ws, 0, zero_bytes, stream);

    int edge_blocks = (n_edges + 3) / 4;  // 4 waves (=4 edges) per 256-thread block
    scatter_agg<<<edge_blocks, 256, 0, stream>>>(X, ei, agg, cnt_col, n_edges);

    linear_relu<<<2048, 256, 0, stream>>>(X, agg, cnt_col, Wl, Wr, b, h, n);

    scatter_gate<<<edge_blocks, 256, 0, stream>>>(h, ei, dsum, cnt_row, n_edges);

    finalize_gate<<<((size_t)n * D + 255) / 256, 256, 0, stream>>>(dsum, cnt_row, out, n);
}

// Round 3
// 859.738 us; speedup vs baseline: 1.0439x; 1.0439x over previous
//
#include <hip/hip_runtime.h>
#include <math.h>

#define D 64

// ---------------------------------------------------------------------------
// Pass 1: degree histogram (int atomics only, 2.5M ops)
// ---------------------------------------------------------------------------
__global__ __launch_bounds__(256) void hist_deg(
    const int* __restrict__ ei, int* __restrict__ deg_col,
    int* __restrict__ deg_row, int n_edges)
{
    int e = blockIdx.x * blockDim.x + threadIdx.x;
    if (e >= n_edges) return;
    atomicAdd(&deg_row[ei[e]], 1);
    atomicAdd(&deg_col[ei[n_edges + e]], 1);
}

// ---------------------------------------------------------------------------
// Pass 2a: per-block exclusive scan (1024 elems/block). Blocks [0,nb) scan A,
// blocks [nb,2nb) scan B. Wave-shfl scan + cross-wave LDS combine.
// ---------------------------------------------------------------------------
__global__ __launch_bounds__(1024) void scan_blocks(
    const int* __restrict__ dA, int* __restrict__ oA, int* __restrict__ tA,
    const int* __restrict__ dB, int* __restrict__ oB, int* __restrict__ tB,
    int n, int nb)
{
    bool isB = blockIdx.x >= (unsigned)nb;
    const int* d = isB ? dB : dA;
    int* o = isB ? oB : oA;
    int* t = isB ? tB : tA;
    int blk = isB ? (blockIdx.x - nb) : blockIdx.x;

    int i = blk * 1024 + threadIdx.x;
    int v = (i < n) ? d[i] : 0;

    int lane = threadIdx.x & 63;
    int wid = threadIdx.x >> 6;       // 16 waves
    int x = v;
    #pragma unroll
    for (int ofs = 1; ofs < 64; ofs <<= 1) {
        int u = __shfl_up(x, ofs);
        if (lane >= ofs) x += u;
    }
    __shared__ int wtot[16];
    __shared__ int woff[16];
    if (lane == 63) wtot[wid] = x;
    __syncthreads();
    if (threadIdx.x < 64) {
        int wv = (lane < 16) ? wtot[lane] : 0;
        int wx = wv;
        #pragma unroll
        for (int ofs = 1; ofs < 16; ofs <<= 1) {
            int u = __shfl_up(wx, ofs);
            if (lane >= ofs) wx += u;
        }
        if (lane < 16) woff[lane] = wx - wv;
    }
    __syncthreads();
    int excl = (x - v) + woff[wid];
    if (i < n) o[i] = excl;
    if (threadIdx.x == 1023) t[blk] = excl + v;
}

// ---------------------------------------------------------------------------
// Pass 2b: scan the per-block totals (nb <= 128). Block 0 -> A, block 1 -> B.
// Also writes off[n] = total (edge count).
// ---------------------------------------------------------------------------
__global__ __launch_bounds__(64) void scan_totals(
    int* __restrict__ tA, int* __restrict__ oA,
    int* __restrict__ tB, int* __restrict__ oB, int nb, int n)
{
    int* t = blockIdx.x ? tB : tA;
    int* o = blockIdx.x ? oB : oA;
    int lane = threadIdx.x & 63;
    int carry = 0;
    for (int base = 0; base < nb; base += 64) {
        int v = (base + lane < nb) ? t[base + lane] : 0;
        int x = v;
        #pragma unroll
        for (int ofs = 1; ofs < 64; ofs <<= 1) {
            int u = __shfl_up(x, ofs);
            if (lane >= ofs) x += u;
        }
        if (base + lane < nb) t[base + lane] = carry + x - v;  // exclusive
        carry += __shfl(x, 63);
    }
    if (lane == 0) o[n] = carry;
}

// ---------------------------------------------------------------------------
// Pass 2c: add block offsets; also materialize cursor copies for the scatter.
// ---------------------------------------------------------------------------
__global__ __launch_bounds__(1024) void add_offsets(
    int* __restrict__ oA, const int* __restrict__ tA, int* __restrict__ cA,
    int* __restrict__ oB, const int* __restrict__ tB, int* __restrict__ cB,
    int n, int nb)
{
    bool isB = blockIdx.x >= (unsigned)nb;
    int* o = isB ? oB : oA;
    const int* t = isB ? tB : tA;
    int* c = isB ? cB : cA;
    int blk = isB ? (blockIdx.x - nb) : blockIdx.x;
    int i = blk * 1024 + threadIdx.x;
    if (i < n) {
        int val = o[i] + t[blk];
        o[i] = val;
        c[i] = val;
    }
}

// ---------------------------------------------------------------------------
// Pass 3: scatter edges into CSR order (int atomics on cursors only)
// by_col[pos] = src  (for in-edge aggregation at each target)
// by_row[pos] = dst  (for out-edge gating at each source)
// ---------------------------------------------------------------------------
__global__ __launch_bounds__(256) void scatter_sort(
    const int* __restrict__ ei, int* __restrict__ cur_col,
    int* __restrict__ cur_row, int* __restrict__ by_col,
    int* __restrict__ by_row, int n_edges)
{
    int e = blockIdx.x * blockDim.x + threadIdx.x;
    if (e >= n_edges) return;
    int r = ei[e];
    int c = ei[n_edges + e];
    int p1 = atomicAdd(&cur_col[c], 1);
    by_col[p1] = r;
    int p2 = atomicAdd(&cur_row[r], 1);
    by_row[p2] = c;
}

// ---------------------------------------------------------------------------
// Pass 4 (fused agg + linear + relu): one wave per node.
// mean in-neighbor aggregate in registers, then h = relu(agg@Wl + b + X@Wr).
// No float atomics; agg never touches memory.
// ---------------------------------------------------------------------------
__global__ __launch_bounds__(256) void agg_linear(
    const float* __restrict__ X, const int* __restrict__ off_col,
    const int* __restrict__ by_col, const float* __restrict__ Wl,
    const float* __restrict__ Wr, const float* __restrict__ b,
    float* __restrict__ h, int n)
{
    __shared__ float sWl[D][D];
    __shared__ float sWr[D][D];
    for (int i = threadIdx.x; i < D * D; i += blockDim.x) {
        sWl[i / D][i % D] = Wl[i];
        sWr[i / D][i % D] = Wr[i];
    }
    __syncthreads();

    int lane = threadIdx.x & 63;
    int waveInBlock = threadIdx.x >> 6;
    int wavesPerBlock = blockDim.x >> 6;
    int nwaves = gridDim.x * wavesPerBlock;
    float bj = b[lane];

    for (int node = blockIdx.x * wavesPerBlock + waveInBlock; node < n;
         node += nwaves) {
        int s0 = off_col[node];
        int s1 = off_col[node + 1];
        float acc = 0.0f;
        for (int base = s0; base < s1; base += 64) {
            int m = s1 - base;
            if (m > 64) m = 64;
            int idx = (lane < m) ? by_col[base + lane] : 0;  // 64 idx / 1 load
            for (int j = 0; j < m; ++j) {
                int r = __shfl(idx, j);
                acc += X[(size_t)r * D + lane];
            }
        }
        float deg = (float)(s1 - s0);
        float a = acc / fmaxf(deg, 1.0f);
        float x = X[(size_t)node * D + lane];
        float hacc = bj;
        #pragma unroll
        for (int k = 0; k < D; ++k) {
            float ak = __shfl(a, k);
            float xk = __shfl(x, k);
            hacc += ak * sWl[k][lane] + xk * sWr[k][lane];
        }
        h[(size_t)node * D + lane] = fmaxf(hacc, 0.0f);
    }
}

// ---------------------------------------------------------------------------
// Pass 5 (fused gate): one wave per node u; h[u] loaded once; accumulate
// (h[u]-h[v])^2 over out-edges in registers; tanh(mean) -> out.
// ---------------------------------------------------------------------------
__global__ __launch_bounds__(256) void gate_kernel(
    const float* __restrict__ h, const int* __restrict__ off_row,
    const int* __restrict__ by_row, float* __restrict__ out, int n)
{
    int lane = threadIdx.x & 63;
    int wave = (blockIdx.x * blockDim.x + threadIdx.x) >> 6;
    if (wave >= n) return;
    int u = wave;
    int s0 = off_row[u];
    int s1 = off_row[u + 1];
    float hu = h[(size_t)u * D + lane];
    float acc = 0.0f;
    for (int base = s0; base < s1; base += 64) {
        int m = s1 - base;
        if (m > 64) m = 64;
        int idx = (lane < m) ? by_row[base + lane] : 0;
        for (int j = 0; j < m; ++j) {
            int c = __shfl(idx, j);
            float d = hu - h[(size_t)c * D + lane];
            acc += d * d;  // P = 2: |d|^2 == d*d
        }
    }
    float deg = (float)(s1 - s0);
    out[(size_t)u * D + lane] = tanhf(acc / fmaxf(deg, 1.0f));
}

extern "C" void kernel_launch(void* const* d_in, const int* in_sizes, int n_in,
                              void* d_out, int out_size, void* d_ws, size_t ws_size,
                              hipStream_t stream) {
    const float* X  = (const float*)d_in[0];
    const int*   ei = (const int*)d_in[1];
    const float* Wl = (const float*)d_in[2];
    const float* Wr = (const float*)d_in[3];
    const float* b  = (const float*)d_in[4];
    float* out = (float*)d_out;

    int n = in_sizes[0] / D;
    int n_edges = in_sizes[1] / 2;
    int nb = (n + 1023) / 1024;  // scan blocks per array

    // workspace layout (all 4-byte elems):
    int* w = (int*)d_ws;
    int* deg_col = w;                        // n
    int* deg_row = deg_col + n;              // n
    int* off_col = deg_row + n;              // n+1
    int* off_row = off_col + (n + 1);        // n+1
    int* cur_col = off_row + (n + 1);        // n
    int* cur_row = cur_col + n;              // n
    int* tot_col = cur_row + n;              // nb
    int* tot_row = tot_col + nb;             // nb
    int* by_col  = tot_row + nb;             // n_edges
    int* by_row  = by_col + n_edges;         // n_edges
    float* h     = (float*)(by_row + n_edges);  // n*D

    hipMemsetAsync(deg_col, 0, (size_t)2 * n * sizeof(int), stream);

    int eb = (n_edges + 255) / 256;
    hist_deg<<<eb, 256, 0, stream>>>(ei, deg_col, deg_row, n_edges);

    scan_blocks<<<2 * nb, 1024, 0, stream>>>(deg_col, off_col, tot_col,
                                             deg_row, off_row, tot_row, n, nb);
    scan_totals<<<2, 64, 0, stream>>>(tot_col, off_col, tot_row, off_row, nb, n);
    add_offsets<<<2 * nb, 1024, 0, stream>>>(off_col, tot_col, cur_col,
                                             off_row, tot_row, cur_row, n, nb);

    scatter_sort<<<eb, 256, 0, stream>>>(ei, cur_col, cur_row, by_col, by_row,
                                         n_edges);

    // grid-stride over nodes; 4 waves per 256-thread block
    agg_linear<<<1280, 256, 0, stream>>>(X, off_col, by_col, Wl, Wr, b, h, n);

    // one wave per node: n waves -> (n+3)/4 blocks of 256 threads
    gate_kernel<<<(n + 3) / 4, 256, 0, stream>>>(h, off_row, by_row, out, n);
}

// Round 4
// 534.046 us; speedup vs baseline: 1.6805x; 1.6099x over previous
//
#include <hip/hip_runtime.h>
#include <math.h>

#define D 64

typedef __attribute__((ext_vector_type(8))) short frag_ab;
typedef __attribute__((ext_vector_type(4))) float frag_cd;

__device__ __forceinline__ unsigned short f2bf(float f) {
    unsigned u = __float_as_uint(f);
    u += 0x7FFFu + ((u >> 16) & 1u);
    return (unsigned short)(u >> 16);
}
__device__ __forceinline__ float bf2f(unsigned short s) {
    return __uint_as_float(((unsigned)s) << 16);
}

// ---------------------------------------------------------------------------
// CSR build: histogram, scan, scatter (unchanged from R3 — verified correct)
// ---------------------------------------------------------------------------
__global__ __launch_bounds__(256) void hist_deg(
    const int* __restrict__ ei, int* __restrict__ deg_col,
    int* __restrict__ deg_row, int n_edges)
{
    int e = blockIdx.x * blockDim.x + threadIdx.x;
    if (e >= n_edges) return;
    atomicAdd(&deg_row[ei[e]], 1);
    atomicAdd(&deg_col[ei[n_edges + e]], 1);
}

__global__ __launch_bounds__(1024) void scan_blocks(
    const int* __restrict__ dA, int* __restrict__ oA, int* __restrict__ tA,
    const int* __restrict__ dB, int* __restrict__ oB, int* __restrict__ tB,
    int n, int nb)
{
    bool isB = blockIdx.x >= (unsigned)nb;
    const int* d = isB ? dB : dA;
    int* o = isB ? oB : oA;
    int* t = isB ? tB : tA;
    int blk = isB ? (blockIdx.x - nb) : blockIdx.x;

    int i = blk * 1024 + threadIdx.x;
    int v = (i < n) ? d[i] : 0;

    int lane = threadIdx.x & 63;
    int wid = threadIdx.x >> 6;
    int x = v;
    #pragma unroll
    for (int ofs = 1; ofs < 64; ofs <<= 1) {
        int u = __shfl_up(x, ofs);
        if (lane >= ofs) x += u;
    }
    __shared__ int wtot[16];
    __shared__ int woff[16];
    if (lane == 63) wtot[wid] = x;
    __syncthreads();
    if (threadIdx.x < 64) {
        int wv = (lane < 16) ? wtot[lane] : 0;
        int wx = wv;
        #pragma unroll
        for (int ofs = 1; ofs < 16; ofs <<= 1) {
            int u = __shfl_up(wx, ofs);
            if (lane >= ofs) wx += u;
        }
        if (lane < 16) woff[lane] = wx - wv;
    }
    __syncthreads();
    int excl = (x - v) + woff[wid];
    if (i < n) o[i] = excl;
    if (threadIdx.x == 1023) t[blk] = excl + v;
}

__global__ __launch_bounds__(64) void scan_totals(
    int* __restrict__ tA, int* __restrict__ oA,
    int* __restrict__ tB, int* __restrict__ oB, int nb, int n)
{
    int* t = blockIdx.x ? tB : tA;
    int* o = blockIdx.x ? oB : oA;
    int lane = threadIdx.x & 63;
    int carry = 0;
    for (int base = 0; base < nb; base += 64) {
        int v = (base + lane < nb) ? t[base + lane] : 0;
        int x = v;
        #pragma unroll
        for (int ofs = 1; ofs < 64; ofs <<= 1) {
            int u = __shfl_up(x, ofs);
            if (lane >= ofs) x += u;
        }
        if (base + lane < nb) t[base + lane] = carry + x - v;
        carry += __shfl(x, 63);
    }
    if (lane == 0) o[n] = carry;
}

__global__ __launch_bounds__(1024) void add_offsets(
    int* __restrict__ oA, const int* __restrict__ tA, int* __restrict__ cA,
    int* __restrict__ oB, const int* __restrict__ tB, int* __restrict__ cB,
    int n, int nb)
{
    bool isB = blockIdx.x >= (unsigned)nb;
    int* o = isB ? oB : oA;
    const int* t = isB ? tB : tA;
    int* c = isB ? cB : cA;
    int blk = isB ? (blockIdx.x - nb) : blockIdx.x;
    int i = blk * 1024 + threadIdx.x;
    if (i < n) {
        int val = o[i] + t[blk];
        o[i] = val;
        c[i] = val;
    }
}

__global__ __launch_bounds__(256) void scatter_sort(
    const int* __restrict__ ei, int* __restrict__ cur_col,
    int* __restrict__ cur_row, int* __restrict__ by_col,
    int* __restrict__ by_row, int n_edges)
{
    int e = blockIdx.x * blockDim.x + threadIdx.x;
    if (e >= n_edges) return;
    int r = ei[e];
    int c = ei[n_edges + e];
    int p1 = atomicAdd(&cur_col[c], 1);
    by_col[p1] = r;
    int p2 = atomicAdd(&cur_row[r], 1);
    by_row[p2] = c;
}

// ---------------------------------------------------------------------------
// Pack Wl/Wr into MFMA B-fragment layout, bf16 hi + lo halves.
// wpack[mat*8192 + half*4096 + (kc*4+nt)*512 + lane*8 + j]
//   = bf16 of W[(lane>>4)*8 + j + kc*32][(lane&15) + nt*16]
// ---------------------------------------------------------------------------
__global__ __launch_bounds__(256) void pack_w(
    const float* __restrict__ Wl, const float* __restrict__ Wr,
    unsigned short* __restrict__ wpack)
{
    for (int c = threadIdx.x; c < 8192; c += 256) {
        int j = c & 7;
        int lane = (c >> 3) & 63;
        int tile = (c >> 9) & 7;  // kc*4+nt
        int mat = c >> 12;
        int kc = tile >> 2;
        int nt = tile & 3;
        int krow = (lane >> 4) * 8 + j + kc * 32;
        int col = (lane & 15) + nt * 16;
        const float* W = mat ? Wr : Wl;
        float v = W[krow * 64 + col];
        unsigned short hi = f2bf(v);
        unsigned short lo = f2bf(v - bf2f(hi));
        int base = mat * 8192 + tile * 512 + lane * 8 + j;
        wpack[base] = hi;
        wpack[base + 4096] = lo;
    }
}

// ---------------------------------------------------------------------------
// CSR mean-aggregate, one wave per node, edge loop unrolled x4 (4 loads
// in flight). Lean kernel: no LDS, low VGPR -> high occupancy.
// ---------------------------------------------------------------------------
__global__ __launch_bounds__(256) void agg_gather(
    const float* __restrict__ X, const int* __restrict__ off_col,
    const int* __restrict__ by_col, float* __restrict__ agg, int n)
{
    int lane = threadIdx.x & 63;
    int node = (blockIdx.x * blockDim.x + threadIdx.x) >> 6;
    if (node >= n) return;
    int s0 = off_col[node], s1 = off_col[node + 1];
    float acc = 0.f;
    for (int base = s0; base < s1; base += 64) {
        int m = s1 - base;
        if (m > 64) m = 64;
        int idx = (lane < m) ? by_col[base + lane] : 0;
        int j = 0;
        for (; j + 4 <= m; j += 4) {
            int r0 = __shfl(idx, j);
            int r1 = __shfl(idx, j + 1);
            int r2 = __shfl(idx, j + 2);
            int r3 = __shfl(idx, j + 3);
            float v0 = X[((size_t)r0 << 6) + lane];
            float v1 = X[((size_t)r1 << 6) + lane];
            float v2 = X[((size_t)r2 << 6) + lane];
            float v3 = X[((size_t)r3 << 6) + lane];
            acc += v0 + v1 + v2 + v3;
        }
        for (; j < m; ++j) {
            int r = __shfl(idx, j);
            acc += X[((size_t)r << 6) + lane];
        }
    }
    float deg = (float)(s1 - s0);
    agg[((size_t)node << 6) + lane] = acc / fmaxf(deg, 1.f);
}

// ---------------------------------------------------------------------------
// h = relu(agg@Wl + X@Wr + b) via MFMA, bf16x3 split (hi*hi + hi*lo + lo*hi).
// One wave per 16-node group. W-frags register-resident from wpack.
// ---------------------------------------------------------------------------
__global__ __launch_bounds__(256) void linear_mfma(
    const float* __restrict__ X, const float* __restrict__ agg,
    const unsigned short* __restrict__ wpack, const float* __restrict__ b,
    float* __restrict__ h, int n, int ngroups)
{
    int lane = threadIdx.x & 63;
    int g = (blockIdx.x * blockDim.x + threadIdx.x) >> 6;
    if (g >= ngroups) return;
    int quad = lane >> 4;
    int l15 = lane & 15;

    frag_ab wf[2][2][2][4];  // [mat][hf][kc][nt]
    #pragma unroll
    for (int mat = 0; mat < 2; ++mat)
        #pragma unroll
        for (int hf = 0; hf < 2; ++hf)
            #pragma unroll
            for (int kc = 0; kc < 2; ++kc)
                #pragma unroll
                for (int nt = 0; nt < 4; ++nt) {
                    const unsigned short* p =
                        wpack + mat * 8192 + hf * 4096 + (kc * 4 + nt) * 512 + lane * 8;
                    wf[mat][hf][kc][nt] = *(const frag_ab*)p;
                }

    frag_cd acc[4];
    #pragma unroll
    for (int nt = 0; nt < 4; ++nt) acc[nt] = (frag_cd){0.f, 0.f, 0.f, 0.f};

    int mrow = g * 16 + l15;
    if (mrow >= n) mrow = n - 1;  // safe clamp (n=100000 is a multiple of 16)
    const float* arow = agg + ((size_t)mrow << 6) + quad * 8;
    const float* xrow = X + ((size_t)mrow << 6) + quad * 8;

    #pragma unroll
    for (int kc = 0; kc < 2; ++kc) {
        float av[8], xv[8];
        #pragma unroll
        for (int t = 0; t < 2; ++t) {
            float4 a4 = *(const float4*)(arow + kc * 32 + t * 4);
            float4 x4 = *(const float4*)(xrow + kc * 32 + t * 4);
            av[t * 4 + 0] = a4.x; av[t * 4 + 1] = a4.y;
            av[t * 4 + 2] = a4.z; av[t * 4 + 3] = a4.w;
            xv[t * 4 + 0] = x4.x; xv[t * 4 + 1] = x4.y;
            xv[t * 4 + 2] = x4.z; xv[t * 4 + 3] = x4.w;
        }
        frag_ab ah, al, xh, xl;
        #pragma unroll
        for (int j = 0; j < 8; ++j) {
            unsigned short hb = f2bf(av[j]);
            ah[j] = (short)hb;
            al[j] = (short)f2bf(av[j] - bf2f(hb));
            unsigned short xb = f2bf(xv[j]);
            xh[j] = (short)xb;
            xl[j] = (short)f2bf(xv[j] - bf2f(xb));
        }
        #pragma unroll
        for (int nt = 0; nt < 4; ++nt) {
            acc[nt] = __builtin_amdgcn_mfma_f32_16x16x32_bf16(ah, wf[0][0][kc][nt], acc[nt], 0, 0, 0);
            acc[nt] = __builtin_amdgcn_mfma_f32_16x16x32_bf16(ah, wf[0][1][kc][nt], acc[nt], 0, 0, 0);
            acc[nt] = __builtin_amdgcn_mfma_f32_16x16x32_bf16(al, wf[0][0][kc][nt], acc[nt], 0, 0, 0);
            acc[nt] = __builtin_amdgcn_mfma_f32_16x16x32_bf16(xh, wf[1][0][kc][nt], acc[nt], 0, 0, 0);
            acc[nt] = __builtin_amdgcn_mfma_f32_16x16x32_bf16(xh, wf[1][1][kc][nt], acc[nt], 0, 0, 0);
            acc[nt] = __builtin_amdgcn_mfma_f32_16x16x32_bf16(xl, wf[1][0][kc][nt], acc[nt], 0, 0, 0);
        }
    }

    #pragma unroll
    for (int nt = 0; nt < 4; ++nt) {
        float bj = b[l15 + nt * 16];
        #pragma unroll
        for (int r = 0; r < 4; ++r) {
            int row = quad * 4 + r;     // C/D layout: row = quad*4 + reg
            int node = g * 16 + row;
            if (node < n) {
                float v = acc[nt][r] + bj;
                h[((size_t)node << 6) + l15 + nt * 16] = fmaxf(v, 0.f);
            }
        }
    }
}

// ---------------------------------------------------------------------------
// Gate: one wave per node u; out-edge loop unrolled x4; tanh(mean) -> out.
// ---------------------------------------------------------------------------
__global__ __launch_bounds__(256) void gate_kernel(
    const float* __restrict__ h, const int* __restrict__ off_row,
    const int* __restrict__ by_row, float* __restrict__ out, int n)
{
    int lane = threadIdx.x & 63;
    int u = (blockIdx.x * blockDim.x + threadIdx.x) >> 6;
    if (u >= n) return;
    int s0 = off_row[u], s1 = off_row[u + 1];
    float hu = h[((size_t)u << 6) + lane];
    float acc = 0.f;
    for (int base = s0; base < s1; base += 64) {
        int m = s1 - base;
        if (m > 64) m = 64;
        int idx = (lane < m) ? by_row[base + lane] : 0;
        int j = 0;
        for (; j + 4 <= m; j += 4) {
            int c0 = __shfl(idx, j);
            int c1 = __shfl(idx, j + 1);
            int c2 = __shfl(idx, j + 2);
            int c3 = __shfl(idx, j + 3);
            float v0 = h[((size_t)c0 << 6) + lane];
            float v1 = h[((size_t)c1 << 6) + lane];
            float v2 = h[((size_t)c2 << 6) + lane];
            float v3 = h[((size_t)c3 << 6) + lane];
            float d0 = hu - v0, d1 = hu - v1, d2 = hu - v2, d3 = hu - v3;
            acc += d0 * d0 + d1 * d1 + d2 * d2 + d3 * d3;
        }
        for (; j < m; ++j) {
            int c = __shfl(idx, j);
            float d = hu - h[((size_t)c << 6) + lane];
            acc += d * d;
        }
    }
    float deg = (float)(s1 - s0);
    out[((size_t)u << 6) + lane] = tanhf(acc / fmaxf(deg, 1.f));
}

extern "C" void kernel_launch(void* const* d_in, const int* in_sizes, int n_in,
                              void* d_out, int out_size, void* d_ws, size_t ws_size,
                              hipStream_t stream) {
    const float* X  = (const float*)d_in[0];
    const int*   ei = (const int*)d_in[1];
    const float* Wl = (const float*)d_in[2];
    const float* Wr = (const float*)d_in[3];
    const float* b  = (const float*)d_in[4];
    float* out = (float*)d_out;

    int n = in_sizes[0] / D;
    int n_edges = in_sizes[1] / 2;
    int nb = (n + 1023) / 1024;

    // ws layout: 16B-aligned float arrays first, then ints
    float* agg = (float*)d_ws;                                  // n*64
    float* h   = agg + (size_t)n * D;                           // n*64
    unsigned short* wpack = (unsigned short*)(h + (size_t)n * D);  // 16384 (32 KB)
    int* w = (int*)(wpack + 16384);
    int* deg_col = w;                         // n
    int* deg_row = deg_col + n;               // n
    int* off_col = deg_row + n;               // n+1
    int* off_row = off_col + (n + 1);         // n+1
    int* cur_col = off_row + (n + 1);         // n
    int* cur_row = cur_col + n;               // n
    int* tot_col = cur_row + n;               // nb
    int* tot_row = tot_col + nb;              // nb
    int* by_col  = tot_row + nb;              // n_edges
    int* by_row  = by_col + n_edges;          // n_edges

    hipMemsetAsync(deg_col, 0, (size_t)2 * n * sizeof(int), stream);

    int eb = (n_edges + 255) / 256;
    hist_deg<<<eb, 256, 0, stream>>>(ei, deg_col, deg_row, n_edges);
    scan_blocks<<<2 * nb, 1024, 0, stream>>>(deg_col, off_col, tot_col,
                                             deg_row, off_row, tot_row, n, nb);
    scan_totals<<<2, 64, 0, stream>>>(tot_col, off_col, tot_row, off_row, nb, n);
    add_offsets<<<2 * nb, 1024, 0, stream>>>(off_col, tot_col, cur_col,
                                             off_row, tot_row, cur_row, n, nb);
    scatter_sort<<<eb, 256, 0, stream>>>(ei, cur_col, cur_row, by_col, by_row,
                                         n_edges);

    pack_w<<<1, 256, 0, stream>>>(Wl, Wr, wpack);

    agg_gather<<<(n + 3) / 4, 256, 0, stream>>>(X, off_col, by_col, agg, n);

    int ngroups = (n + 15) / 16;
    linear_mfma<<<(ngroups + 3) / 4, 256, 0, stream>>>(X, agg, wpack, b, h, n,
                                                       ngroups);

    gate_kernel<<<(n + 3) / 4, 256, 0, stream>>>(h, off_row, by_row, out, n);
}